// Round 2
// baseline (946.206 us; speedup 1.0000x reference)
//
#include <hip/hip_runtime.h>
#include <hip/hip_bf16.h>
#include <cstdint>
#include <cstddef>

// Problem constants
#define E_   8
#define H_   2048
#define I_   2816
#define T_   512
#define NPAIR 1024         // T*K (token,k) pairs

// GEMM tiling
#define TM   192           // one m-tile per expert w.h.p. -> weights streamed once
#define TN   16            // narrow N: direct-from-global B fragments, low VGPR
#define BK   64
#define MT_  3             // m-frags per wave (192 / 4 waves / 16)

typedef __attribute__((ext_vector_type(8))) short          bf16x8;
typedef __attribute__((ext_vector_type(4))) float          f32x4;
typedef __attribute__((ext_vector_type(8))) unsigned short u16x8;

__device__ __forceinline__ unsigned short f2bf(float f){
  union { float f; unsigned u; } a; a.f = f;
  unsigned u = a.u;
  unsigned r = u + 0x7fffu + ((u >> 16) & 1u);   // RNE
  return (unsigned short)(r >> 16);
}

// Pack 4 floats (x scale) to 4 bf16 via packed HW cvt
__device__ __forceinline__ void cvt4(u16x8& dst, int base, const float4 v, float s){
  __hip_bfloat162 p0 = __float22bfloat162_rn(float2{v.x*s, v.y*s});
  __hip_bfloat162 p1 = __float22bfloat162_rn(float2{v.z*s, v.w*s});
  union { __hip_bfloat162 b; unsigned u; } a0{p0}, a1{p1};
  dst[base+0] = (unsigned short)(a0.u & 0xffff);
  dst[base+1] = (unsigned short)(a0.u >> 16);
  dst[base+2] = (unsigned short)(a1.u & 0xffff);
  dst[base+3] = (unsigned short)(a1.u >> 16);
}

__device__ __forceinline__ bf16x8 u2b(u16x8 v){
  union { u16x8 u; bf16x8 b; } x; x.u = v; return x.b;
}

// ---------------------------------------------------------------------------
// Routing: bucket 1024 (t,k) pairs by expert; also inverse map slot-of-pair.
// ---------------------------------------------------------------------------
__global__ void route_kernel(const int* __restrict__ ids,
                             int* __restrict__ offs, int* __restrict__ ptok,
                             int* __restrict__ sop){
  __shared__ int scnt[E_];
  __shared__ int scur[E_];
  const int tid = threadIdx.x;
  if (tid < E_) scnt[tid] = 0;
  __syncthreads();
  const int e = ids[tid];
  atomicAdd(&scnt[e], 1);
  __syncthreads();
  if (tid == 0){
    int s = 0;
    for (int i = 0; i < E_; i++){ offs[i] = s; scur[i] = s; s += scnt[i]; }
    offs[E_] = s;
  }
  __syncthreads();
  const int pos = atomicAdd(&scur[e], 1);
  ptok[pos] = tid >> 1;
  sop[tid]  = pos;
}

// ---------------------------------------------------------------------------
// Prep: gather+convert x rows into slot order, bf16. xg[slot][H]
// ---------------------------------------------------------------------------
__global__ void prep_kernel(const float* __restrict__ x, const int* __restrict__ ptok,
                            unsigned short* __restrict__ xg){
  const int slot = blockIdx.x;
  const int tok  = ptok[slot];
  const int k0   = threadIdx.x * 8;
  const float4 v0 = *(const float4*)(x + (size_t)tok*H_ + k0);
  const float4 v1 = *(const float4*)(x + (size_t)tok*H_ + k0 + 4);
  u16x8 o;
  cvt4(o, 0, v0, 1.f);
  cvt4(o, 4, v1, 1.f);
  *(u16x8*)(xg + (size_t)slot*H_ + k0) = o;
}

// ---------------------------------------------------------------------------
// GEMM1: act[slot,i] = silu(x@Wg^T)*(x@Wu^T).
// Barrier-free / LDS-free: every wave loads its B fragments DIRECTLY from
// global in fragment order (f32 -> x scale -> RNE bf16, in registers), with a
// one-tile register ring (S0/S1 per K-half). Waves free-run like a streaming
// copy kernel; the 4x per-block B redundancy is served by L1/L2 (all waves of
// a block read identical lines; HBM unique bytes unchanged).
// XCD pinning: blockIdx.x == expert, gridDim.x == 8 == #XCDs.
// grid: (E=8, I/TN=176, 6), block 256.
// ---------------------------------------------------------------------------
__global__ __launch_bounds__(256, 3)
void gemm1_kernel(const unsigned short* __restrict__ xg, const float* __restrict__ w13,
                  const float* __restrict__ s13, const int* __restrict__ offs,
                  unsigned short* __restrict__ act)
{
  const int e   = blockIdx.x;
  const int off = offs[e];
  const int cnt = offs[e+1] - off;
  const int m0  = blockIdx.z * TM;
  if (m0 >= cnt) return;
  const int rows = min(TM, cnt - m0);
  const int nb   = blockIdx.y * TN;

  const int tid  = threadIdx.x;
  const int wave = tid >> 6;
  const int lane = tid & 63;
  const int quad = lane >> 4;
  const int l16  = lane & 15;

  const float* w13e = w13 + (size_t)e * (2*I_) * H_;
  const float* s13e = s13 + (size_t)e * (2*I_/128) * (H_/128);

  // B fragment row pointers: hh=0 gate, hh=1 up; row = hh*I_ + nb + l16
  const float* bP[2];
  bP[0] = w13e + (size_t)(nb + l16) * H_ + quad*8;
  bP[1] = w13e + (size_t)(I_ + nb + l16) * H_ + quad*8;
  // scale rows (uniform across the block's 16 output cols since 16 | 128)
  const int s0row = (nb >> 7) * (H_/128);
  const int s1row = ((I_/128) + (nb >> 7)) * (H_/128);

  // A fragment row pointers (clamped; OOB rows discarded in epilogue)
  const unsigned short* aP[MT_];
  #pragma unroll
  for (int mt = 0; mt < MT_; mt++){
    int sl = off + m0 + wave*(TM/4) + mt*16 + l16;
    sl = min(sl, NPAIR - 1);
    aP[mt] = xg + (size_t)sl * H_ + quad*8;
  }

  f32x4 acc[2][MT_];
  #pragma unroll
  for (int h = 0; h < 2; h++)
    #pragma unroll
    for (int mt = 0; mt < MT_; mt++)
      acc[h][mt] = (f32x4){0.f, 0.f, 0.f, 0.f};

  float4 S0[4], S1[4];            // f32 B staging: kk=0 / kk=1 halves
  bf16x8 A0[2][MT_], A1[2][MT_];  // A double buffer (full tiles)

  auto loadBhalf = [&](int t, int kk, float4* S){
    #pragma unroll
    for (int hh = 0; hh < 2; hh++){
      const float* p = bP[hh] + t*BK + kk*32;
      S[2*hh]   = *(const float4*)p;
      S[2*hh+1] = *(const float4*)(p + 4);
    }
  };
  auto loadA = [&](int t, bf16x8 (*A)[MT_]){
    #pragma unroll
    for (int kk = 0; kk < 2; kk++)
      #pragma unroll
      for (int mt = 0; mt < MT_; mt++)
        A[kk][mt] = *(const bf16x8*)(aP[mt] + t*BK + kk*32);
  };
  auto mfmaHalf = [&](int kk, bf16x8 (*A)[MT_], const float4* S, float sg, float su){
    #pragma unroll
    for (int hh = 0; hh < 2; hh++){
      u16x8 o;
      const float s = hh ? su : sg;
      cvt4(o, 0, S[2*hh],   s);
      cvt4(o, 4, S[2*hh+1], s);
      const bf16x8 bv = u2b(o);
      #pragma unroll
      for (int mt = 0; mt < MT_; mt++)
        acc[hh][mt] = __builtin_amdgcn_mfma_f32_16x16x32_bf16(A[kk][mt], bv, acc[hh][mt], 0, 0, 0);
    }
  };

  const int NITER = H_/BK;   // 32 (even)
  loadBhalf(0, 0, S0);
  loadBhalf(0, 1, S1);
  loadA(0, A0);

  for (int t = 0; t < NITER; t += 2){
    const float sg = s13e[s0row + (t >> 1)];
    const float su = s13e[s1row + (t >> 1)];
    // tile t (A0)
    loadA(t+1, A1);
    mfmaHalf(0, A0, S0, sg, su);
    loadBhalf(t+1, 0, S0);
    mfmaHalf(1, A0, S1, sg, su);
    loadBhalf(t+1, 1, S1);
    // tile t+1 (A1) -- same 128-wide scale block
    if (t+2 < NITER) loadA(t+2, A0);
    mfmaHalf(0, A1, S0, sg, su);
    if (t+2 < NITER) loadBhalf(t+2, 0, S0);
    mfmaHalf(1, A1, S1, sg, su);
    if (t+2 < NITER) loadBhalf(t+2, 1, S1);
  }

  // epilogue: act = silu(gate)*up
  #pragma unroll
  for (int mt = 0; mt < MT_; mt++){
    #pragma unroll
    for (int r = 0; r < 4; r++){
      const int m = wave*(TM/4) + mt*16 + quad*4 + r;
      if (m < rows){
        const float g = acc[0][mt][r];
        const float u = acc[1][mt][r];
        const float sg2 = g / (1.f + __expf(-g));
        act[(size_t)(off + m0 + m)*I_ + (nb + l16)] = f2bf(sg2 * u);
      }
    }
  }
}

// ---------------------------------------------------------------------------
// GEMM2: buf[slot,h] = act @ W2^T. Same barrier-free direct-B structure.
// grid: (E=8, H/TN=128, 6), block 256.
// ---------------------------------------------------------------------------
__global__ __launch_bounds__(256, 3)
void gemm2_kernel(const unsigned short* __restrict__ act, const float* __restrict__ w2,
                  const float* __restrict__ s2, const int* __restrict__ offs,
                  float* __restrict__ buf)
{
  const int e   = blockIdx.x;
  const int off = offs[e];
  const int cnt = offs[e+1] - off;
  const int m0  = blockIdx.z * TM;
  if (m0 >= cnt) return;
  const int rows = min(TM, cnt - m0);
  const int nb   = blockIdx.y * TN;

  const int tid  = threadIdx.x;
  const int wave = tid >> 6;
  const int lane = tid & 63;
  const int quad = lane >> 4;
  const int l16  = lane & 15;

  const float* w2e = w2 + (size_t)e * H_ * I_;
  const float* s2e = s2 + (size_t)e * (H_/128) * (I_/128);

  const float* bP = w2e + (size_t)(nb + l16) * I_ + quad*8;
  const int srow  = (nb >> 7) * (I_/128);

  const unsigned short* aP[MT_];
  #pragma unroll
  for (int mt = 0; mt < MT_; mt++){
    int sl = off + m0 + wave*(TM/4) + mt*16 + l16;
    sl = min(sl, NPAIR - 1);
    aP[mt] = act + (size_t)sl * I_ + quad*8;
  }

  f32x4 acc[MT_];
  #pragma unroll
  for (int mt = 0; mt < MT_; mt++)
    acc[mt] = (f32x4){0.f, 0.f, 0.f, 0.f};

  float4 S0[2], S1[2];
  bf16x8 A0[2][MT_], A1[2][MT_];

  auto loadBhalf = [&](int t, int kk, float4* S){
    const float* p = bP + t*BK + kk*32;
    S[0] = *(const float4*)p;
    S[1] = *(const float4*)(p + 4);
  };
  auto loadA = [&](int t, bf16x8 (*A)[MT_]){
    #pragma unroll
    for (int kk = 0; kk < 2; kk++)
      #pragma unroll
      for (int mt = 0; mt < MT_; mt++)
        A[kk][mt] = *(const bf16x8*)(aP[mt] + t*BK + kk*32);
  };
  auto mfmaHalf = [&](int kk, bf16x8 (*A)[MT_], const float4* S, float s){
    u16x8 o;
    cvt4(o, 0, S[0], s);
    cvt4(o, 4, S[1], s);
    const bf16x8 bv = u2b(o);
    #pragma unroll
    for (int mt = 0; mt < MT_; mt++)
      acc[mt] = __builtin_amdgcn_mfma_f32_16x16x32_bf16(A[kk][mt], bv, acc[mt], 0, 0, 0);
  };

  const int NITER = I_/BK;   // 44 (even)
  loadBhalf(0, 0, S0);
  loadBhalf(0, 1, S1);
  loadA(0, A0);

  for (int t = 0; t < NITER; t += 2){
    const float s = s2e[srow + (t >> 1)];
    // tile t (A0)
    loadA(t+1, A1);
    mfmaHalf(0, A0, S0, s);
    loadBhalf(t+1, 0, S0);
    mfmaHalf(1, A0, S1, s);
    loadBhalf(t+1, 1, S1);
    // tile t+1 (A1)
    if (t+2 < NITER) loadA(t+2, A0);
    mfmaHalf(0, A1, S0, s);
    if (t+2 < NITER) loadBhalf(t+2, 0, S0);
    mfmaHalf(1, A1, S1, s);
    if (t+2 < NITER) loadBhalf(t+2, 1, S1);
  }

  // epilogue: plain stores per slot row
  #pragma unroll
  for (int mt = 0; mt < MT_; mt++){
    #pragma unroll
    for (int r = 0; r < 4; r++){
      const int m = wave*(TM/4) + mt*16 + quad*4 + r;
      if (m < rows)
        buf[(size_t)(off + m0 + m)*H_ + (nb + l16)] = acc[mt][r];
    }
  }
}

// ---------------------------------------------------------------------------
// Combine: out[t,:] = tw[2t]*buf[sop[2t],:] + tw[2t+1]*buf[sop[2t+1],:]
// ---------------------------------------------------------------------------
__global__ void combine_kernel(const float* __restrict__ buf, const int* __restrict__ sop,
                               const float* __restrict__ tw, float* __restrict__ out){
  const int gid = blockIdx.x*256 + threadIdx.x;
  const int t = gid >> 9;
  const int c = gid & 511;
  const int s0 = sop[2*t], s1 = sop[2*t+1];
  const float w0 = tw[2*t], w1 = tw[2*t+1];
  const float4 v0 = ((const float4*)buf)[(size_t)s0*(H_/4) + c];
  const float4 v1 = ((const float4*)buf)[(size_t)s1*(H_/4) + c];
  float4 o;
  o.x = w0*v0.x + w1*v1.x;
  o.y = w0*v0.y + w1*v1.y;
  o.z = w0*v0.z + w1*v1.z;
  o.w = w0*v0.w + w1*v1.w;
  ((float4*)out)[gid] = o;
}

// ---------------------------------------------------------------------------
extern "C" void kernel_launch(void* const* d_in, const int* in_sizes, int n_in,
                              void* d_out, int out_size, void* d_ws, size_t ws_size,
                              hipStream_t stream){
  const float* x   = (const float*)d_in[0];
  const int*   ids = (const int*)  d_in[1];
  const float* tw  = (const float*)d_in[2];
  const float* w13 = (const float*)d_in[3];
  const float* s13 = (const float*)d_in[4];
  const float* w2  = (const float*)d_in[5];
  const float* s2  = (const float*)d_in[6];
  float* out = (float*)d_out;

  char* ws = (char*)d_ws;
  int* offs = (int*)ws;                                   // 9 ints
  int* ptok = (int*)(ws + 64);                            // 1024 ints
  int* sop  = (int*)(ws + 64 + 4096);                     // 1024 ints
  unsigned short* xg  = (unsigned short*)(ws + 16384);    // [1024][H] bf16 (aliased by buf)
  float*          buf = (float*)(ws + 16384);             // [1024][H] f32
  unsigned short* act = (unsigned short*)(ws + 16384 + (size_t)NPAIR*H_*4);  // [1024][I] bf16

  route_kernel  <<<1, NPAIR, 0, stream>>>(ids, offs, ptok, sop);
  prep_kernel   <<<NPAIR, 256, 0, stream>>>(x, ptok, xg);
  gemm1_kernel  <<<dim3(E_, I_/TN, (NPAIR + TM - 1)/TM), 256, 0, stream>>>(xg, w13, s13, offs, act);
  gemm2_kernel  <<<dim3(E_, H_/TN, (NPAIR + TM - 1)/TM), 256, 0, stream>>>(act, w2, s2, offs, buf);
  combine_kernel<<<(T_*H_/4)/256, 256, 0, stream>>>(buf, sop, tw, out);
}

// Round 3
// 700.877 us; speedup vs baseline: 1.3500x; 1.3500x over previous
//
#include <hip/hip_runtime.h>
#include <hip/hip_bf16.h>
#include <cstdint>
#include <cstddef>

// Problem constants
#define E_   8
#define H_   2048
#define I_   2816
#define T_   512
#define NPAIR 1024         // T*K (token,k) pairs

// GEMM tiling
#define TM   192           // one m-tile per expert w.h.p. -> weights streamed once
#define TN   32
#define BK   64
#define MT_  3             // m-frags per wave (192 / 4 waves / 16)

typedef __attribute__((ext_vector_type(8))) short          bf16x8;
typedef __attribute__((ext_vector_type(4))) float          f32x4;
typedef __attribute__((ext_vector_type(8))) unsigned short u16x8;

__device__ __forceinline__ unsigned short f2bf(float f){
  union { float f; unsigned u; } a; a.f = f;
  unsigned u = a.u;
  unsigned r = u + 0x7fffu + ((u >> 16) & 1u);   // RNE
  return (unsigned short)(r >> 16);
}

__device__ __forceinline__ void cvt4(u16x8& dst, int base, const float4 v, float s){
  __hip_bfloat162 p0 = __float22bfloat162_rn(float2{v.x*s, v.y*s});
  __hip_bfloat162 p1 = __float22bfloat162_rn(float2{v.z*s, v.w*s});
  union { __hip_bfloat162 b; unsigned u; } a0{p0}, a1{p1};
  dst[base+0] = (unsigned short)(a0.u & 0xffff);
  dst[base+1] = (unsigned short)(a0.u >> 16);
  dst[base+2] = (unsigned short)(a1.u & 0xffff);
  dst[base+3] = (unsigned short)(a1.u >> 16);
}

__device__ __forceinline__ bf16x8 u2b(u16x8 v){
  union { u16x8 u; bf16x8 b; } x; x.u = v; return x.b;
}

// async global->LDS, 16B per lane. LDS dest = wave-uniform base + lane*16.
__device__ __forceinline__ void gload_lds16(const void* g, void* l){
  __builtin_amdgcn_global_load_lds(
      (const __attribute__((address_space(1))) unsigned int*)g,
      (__attribute__((address_space(3))) unsigned int*)l, 16, 0, 0);
}

// ---------------------------------------------------------------------------
// Routing: bucket 1024 (t,k) pairs by expert; also inverse map slot-of-pair.
// ---------------------------------------------------------------------------
__global__ void route_kernel(const int* __restrict__ ids,
                             int* __restrict__ offs, int* __restrict__ ptok,
                             int* __restrict__ sop){
  __shared__ int scnt[E_];
  __shared__ int scur[E_];
  const int tid = threadIdx.x;
  if (tid < E_) scnt[tid] = 0;
  __syncthreads();
  const int e = ids[tid];
  atomicAdd(&scnt[e], 1);
  __syncthreads();
  if (tid == 0){
    int s = 0;
    for (int i = 0; i < E_; i++){ offs[i] = s; scur[i] = s; s += scnt[i]; }
    offs[E_] = s;
  }
  __syncthreads();
  const int pos = atomicAdd(&scur[e], 1);
  ptok[pos] = tid >> 1;
  sop[tid]  = pos;
}

// ---------------------------------------------------------------------------
// Prep: gather+convert x rows into slot order, bf16. xg[slot][H]
// ---------------------------------------------------------------------------
__global__ void prep_kernel(const float* __restrict__ x, const int* __restrict__ ptok,
                            unsigned short* __restrict__ xg){
  const int slot = blockIdx.x;
  const int tok  = ptok[slot];
  const int k0   = threadIdx.x * 8;
  const float4 v0 = *(const float4*)(x + (size_t)tok*H_ + k0);
  const float4 v1 = *(const float4*)(x + (size_t)tok*H_ + k0 + 4);
  u16x8 o;
  cvt4(o, 0, v0, 1.f);
  cvt4(o, 4, v1, 1.f);
  *(u16x8*)(xg + (size_t)slot*H_ + k0) = o;
}

// ---------------------------------------------------------------------------
// GEMM1: act[slot,i] = silu(x@Wg^T)*(x@Wu^T).
// B path: f32 tiles DMA'd global->LDS via global_load_lds into a 3-deep ring,
// counted vmcnt waits (never drain): stage issue distance = 2 tiles (~2x
// compute time) covers HBM latency; next-tile stage + next A-load stay in
// flight across every barrier. Dequant (x scale -> RNE bf16) happens at
// LDS->reg read. Bank conflicts: both-sides XOR swizzle, 16B granule,
// x = (row&7)<<4 bytes (pre-swizzled global source, XOR'd ds_read).
// XCD pinning: blockIdx.x == expert, gridDim.x == 8 == #XCDs.
// grid: (E=8, I/TN=88, 6), block 256.
// ---------------------------------------------------------------------------
__global__ __launch_bounds__(256, 3)
void gemm1_kernel(const unsigned short* __restrict__ xg, const float* __restrict__ w13,
                  const float* __restrict__ s13, const int* __restrict__ offs,
                  unsigned short* __restrict__ act)
{
  const int e   = blockIdx.x;
  const int off = offs[e];
  const int cnt = offs[e+1] - off;
  const int m0  = blockIdx.z * TM;
  if (m0 >= cnt) return;
  const int rows = min(TM, cnt - m0);
  const int nb   = blockIdx.y * TN;

  __shared__ __align__(16) float Bs[3][2*TN][BK];   // 3 x 16KB ring

  const int tid  = threadIdx.x;
  const int wv   = tid >> 6;
  const int lane = tid & 63;
  const int quad = lane >> 4;
  const int l16  = lane & 15;

  const float* w13e = w13 + (size_t)e * (2*I_) * H_;
  const float* s13e = s13 + (size_t)e * (2*I_/128) * (H_/128);

  // scale rows (uniform across block: 32 | 128)
  const int s0row = (nb >> 7) * (H_/128);
  const int s1row = ((I_/128) + (nb >> 7)) * (H_/128);

  // Staging: wave wv stages LDS rows [wv*16, wv*16+16), 4 insts x 4 rows.
  // Pre-swizzled global source: col byte = ((lane&15)*16) ^ ((row&7)<<4).
  const char* srcP[4];
  #pragma unroll
  for (int j = 0; j < 4; j++){
    const int rl = wv*16 + j*4 + (lane >> 4);
    const int gr = (rl < TN) ? (nb + rl) : (I_ + nb + (rl - TN));
    const int cb = ((lane & 15) << 4) ^ ((rl & 7) << 4);
    srcP[j] = (const char*)(w13e + (size_t)gr * H_) + cb;
  }
  auto stage = [&](int t, int slot){
    #pragma unroll
    for (int j = 0; j < 4; j++)
      gload_lds16(srcP[j] + (size_t)t * (BK*4), &Bs[slot][wv*16 + j*4][0]);
  };

  // A fragment row pointers (clamped; OOB rows discarded in epilogue)
  const unsigned short* aP[MT_];
  #pragma unroll
  for (int mt = 0; mt < MT_; mt++){
    int sl = off + m0 + wv*(TM/4) + mt*16 + l16;
    sl = min(sl, NPAIR - 1);
    aP[mt] = xg + (size_t)sl * H_ + quad*8;
  }

  f32x4 acc[2][MT_][2];
  #pragma unroll
  for (int h = 0; h < 2; h++)
    #pragma unroll
    for (int mt = 0; mt < MT_; mt++)
      #pragma unroll
      for (int nt = 0; nt < 2; nt++)
        acc[h][mt][nt] = (f32x4){0.f, 0.f, 0.f, 0.f};

  bf16x8 A0[2][MT_], A1[2][MT_];
  auto loadA = [&](int t, bf16x8 (*A)[MT_]){
    #pragma unroll
    for (int kk = 0; kk < 2; kk++)
      #pragma unroll
      for (int mt = 0; mt < MT_; mt++)
        A[kk][mt] = *(const bf16x8*)(aP[mt] + t*BK + kk*32);
  };

  auto comp = [&](int slot, bf16x8 (*A)[MT_], float sg, float su){
    #pragma unroll
    for (int kk = 0; kk < 2; kk++)
      #pragma unroll
      for (int hh = 0; hh < 2; hh++){
        const float s = hh ? su : sg;
        #pragma unroll
        for (int nt = 0; nt < 2; nt++){
          const int row = hh*TN + nt*16 + l16;
          const int xr  = (row & 7) << 2;            // float units (=16B)
          const int cb  = kk*32 + quad*8;
          const float4 F0 = *(const float4*)&Bs[slot][row][cb ^ xr];
          const float4 F1 = *(const float4*)&Bs[slot][row][(cb + 4) ^ xr];
          u16x8 o; cvt4(o, 0, F0, s); cvt4(o, 4, F1, s);
          const bf16x8 bv = u2b(o);
          #pragma unroll
          for (int mt = 0; mt < MT_; mt++)
            acc[hh][mt][nt] = __builtin_amdgcn_mfma_f32_16x16x32_bf16(A[kk][mt], bv, acc[hh][mt][nt], 0, 0, 0);
        }
      }
  };

  const int NITER = H_/BK;   // 32
  // prologue: A(0) oldest, then stage(0), stage(1)
  loadA(0, A0);
  stage(0, 0);
  stage(1, 1);
  asm volatile("s_waitcnt vmcnt(4)" ::: "memory");   // A(0)+stage(0) done; stage(1) in flight
  __builtin_amdgcn_s_barrier();
  stage(2, 2);
  loadA(1, A1);
  comp(0, A0, s13e[s0row], s13e[s1row]);

  int cs = 1, ss = 0;   // cs = t%3, ss = (t+2)%3 for t=1
  for (int t = 1; t < NITER-1; t++){
    // own stage(t) done; stage(t+1)(4) + loadA(t)(6) stay in flight
    asm volatile("s_waitcnt vmcnt(10)" ::: "memory");
    __builtin_amdgcn_s_barrier();
    if (t+2 < NITER) stage(t+2, ss);
    loadA(t+1, (t & 1) ? A0 : A1);
    const float sg = s13e[s0row + (t >> 1)];
    const float su = s13e[s1row + (t >> 1)];
    comp(cs, (t & 1) ? A1 : A0, sg, su);
    cs = (cs == 2) ? 0 : cs + 1;
    ss = (ss == 2) ? 0 : ss + 1;
  }
  {  // final tile: only loadA(NITER-1)(6) still in flight after the wait
    asm volatile("s_waitcnt vmcnt(6)" ::: "memory");
    __builtin_amdgcn_s_barrier();
    const int t = NITER-1;
    comp(cs, (t & 1) ? A1 : A0, s13e[s0row + (t >> 1)], s13e[s1row + (t >> 1)]);
  }

  // epilogue: act = silu(gate)*up
  #pragma unroll
  for (int mt = 0; mt < MT_; mt++){
    #pragma unroll
    for (int nt = 0; nt < 2; nt++){
      #pragma unroll
      for (int r = 0; r < 4; r++){
        const int m = wv*(TM/4) + mt*16 + quad*4 + r;
        if (m < rows){
          const float g = acc[0][mt][nt][r];
          const float u = acc[1][mt][nt][r];
          const float sg2 = g / (1.f + __expf(-g));
          act[(size_t)(off + m0 + m)*I_ + (nb + nt*16 + l16)] = f2bf(sg2 * u);
        }
      }
    }
  }
}

// ---------------------------------------------------------------------------
// GEMM2: buf[slot,h] = act @ W2^T. Same ring pipeline; tile = 32 rows (8KB).
// grid: (E=8, H/TN=64, 6), block 256.
// ---------------------------------------------------------------------------
__global__ __launch_bounds__(256, 3)
void gemm2_kernel(const unsigned short* __restrict__ act, const float* __restrict__ w2,
                  const float* __restrict__ s2, const int* __restrict__ offs,
                  float* __restrict__ buf)
{
  const int e   = blockIdx.x;
  const int off = offs[e];
  const int cnt = offs[e+1] - off;
  const int m0  = blockIdx.z * TM;
  if (m0 >= cnt) return;
  const int rows = min(TM, cnt - m0);
  const int nb   = blockIdx.y * TN;

  __shared__ __align__(16) float Bs[3][TN][BK];   // 3 x 8KB ring

  const int tid  = threadIdx.x;
  const int wv   = tid >> 6;
  const int lane = tid & 63;
  const int quad = lane >> 4;
  const int l16  = lane & 15;

  const float* w2e = w2 + (size_t)e * H_ * I_;
  const float* s2e = s2 + (size_t)e * (H_/128) * (I_/128);
  const int srow  = (nb >> 7) * (I_/128);

  // Staging: wave wv stages rows [wv*8, wv*8+8), 2 insts x 4 rows.
  const char* srcP[2];
  #pragma unroll
  for (int j = 0; j < 2; j++){
    const int rl = wv*8 + j*4 + (lane >> 4);
    const int cb = ((lane & 15) << 4) ^ ((rl & 7) << 4);
    srcP[j] = (const char*)(w2e + (size_t)(nb + rl) * I_) + cb;
  }
  auto stage = [&](int t, int slot){
    #pragma unroll
    for (int j = 0; j < 2; j++)
      gload_lds16(srcP[j] + (size_t)t * (BK*4), &Bs[slot][wv*8 + j*4][0]);
  };

  const unsigned short* aP[MT_];
  #pragma unroll
  for (int mt = 0; mt < MT_; mt++){
    int sl = off + m0 + wv*(TM/4) + mt*16 + l16;
    sl = min(sl, NPAIR - 1);
    aP[mt] = act + (size_t)sl * I_ + quad*8;
  }

  f32x4 acc[MT_][2];
  #pragma unroll
  for (int mt = 0; mt < MT_; mt++)
    #pragma unroll
    for (int nt = 0; nt < 2; nt++)
      acc[mt][nt] = (f32x4){0.f, 0.f, 0.f, 0.f};

  bf16x8 A0[2][MT_], A1[2][MT_];
  auto loadA = [&](int t, bf16x8 (*A)[MT_]){
    #pragma unroll
    for (int kk = 0; kk < 2; kk++)
      #pragma unroll
      for (int mt = 0; mt < MT_; mt++)
        A[kk][mt] = *(const bf16x8*)(aP[mt] + t*BK + kk*32);
  };

  auto comp = [&](int slot, bf16x8 (*A)[MT_], float s){
    #pragma unroll
    for (int kk = 0; kk < 2; kk++)
      #pragma unroll
      for (int nt = 0; nt < 2; nt++){
        const int row = nt*16 + l16;
        const int xr  = (row & 7) << 2;
        const int cb  = kk*32 + quad*8;
        const float4 F0 = *(const float4*)&Bs[slot][row][cb ^ xr];
        const float4 F1 = *(const float4*)&Bs[slot][row][(cb + 4) ^ xr];
        u16x8 o; cvt4(o, 0, F0, s); cvt4(o, 4, F1, s);
        const bf16x8 bv = u2b(o);
        #pragma unroll
        for (int mt = 0; mt < MT_; mt++)
          acc[mt][nt] = __builtin_amdgcn_mfma_f32_16x16x32_bf16(A[kk][mt], bv, acc[mt][nt], 0, 0, 0);
      }
  };

  const int NITER = I_/BK;   // 44
  loadA(0, A0);
  stage(0, 0);
  stage(1, 1);
  asm volatile("s_waitcnt vmcnt(2)" ::: "memory");   // A(0)+stage(0) done; stage(1) in flight
  __builtin_amdgcn_s_barrier();
  stage(2, 2);
  loadA(1, A1);
  comp(0, A0, s2e[srow]);

  int cs = 1, ss = 0;
  for (int t = 1; t < NITER-1; t++){
    // own stage(t) done; stage(t+1)(2) + loadA(t)(6) stay in flight
    asm volatile("s_waitcnt vmcnt(8)" ::: "memory");
    __builtin_amdgcn_s_barrier();
    if (t+2 < NITER) stage(t+2, ss);
    loadA(t+1, (t & 1) ? A0 : A1);
    comp(cs, (t & 1) ? A1 : A0, s2e[srow + (t >> 1)]);
    cs = (cs == 2) ? 0 : cs + 1;
    ss = (ss == 2) ? 0 : ss + 1;
  }
  {
    asm volatile("s_waitcnt vmcnt(6)" ::: "memory");
    __builtin_amdgcn_s_barrier();
    const int t = NITER-1;
    comp(cs, (t & 1) ? A1 : A0, s2e[srow + (t >> 1)]);
  }

  // epilogue: plain stores per slot row
  #pragma unroll
  for (int mt = 0; mt < MT_; mt++){
    #pragma unroll
    for (int nt = 0; nt < 2; nt++){
      #pragma unroll
      for (int r = 0; r < 4; r++){
        const int m = wv*(TM/4) + mt*16 + quad*4 + r;
        if (m < rows)
          buf[(size_t)(off + m0 + m)*H_ + (nb + nt*16 + l16)] = acc[mt][nt][r];
      }
    }
  }
}

// ---------------------------------------------------------------------------
// Combine: out[t,:] = tw[2t]*buf[sop[2t],:] + tw[2t+1]*buf[sop[2t+1],:]
// ---------------------------------------------------------------------------
__global__ void combine_kernel(const float* __restrict__ buf, const int* __restrict__ sop,
                               const float* __restrict__ tw, float* __restrict__ out){
  const int gid = blockIdx.x*256 + threadIdx.x;
  const int t = gid >> 9;
  const int c = gid & 511;
  const int s0 = sop[2*t], s1 = sop[2*t+1];
  const float w0 = tw[2*t], w1 = tw[2*t+1];
  const float4 v0 = ((const float4*)buf)[(size_t)s0*(H_/4) + c];
  const float4 v1 = ((const float4*)buf)[(size_t)s1*(H_/4) + c];
  float4 o;
  o.x = w0*v0.x + w1*v1.x;
  o.y = w0*v0.y + w1*v1.y;
  o.z = w0*v0.z + w1*v1.z;
  o.w = w0*v0.w + w1*v1.w;
  ((float4*)out)[gid] = o;
}

// ---------------------------------------------------------------------------
extern "C" void kernel_launch(void* const* d_in, const int* in_sizes, int n_in,
                              void* d_out, int out_size, void* d_ws, size_t ws_size,
                              hipStream_t stream){
  const float* x   = (const float*)d_in[0];
  const int*   ids = (const int*)  d_in[1];
  const float* tw  = (const float*)d_in[2];
  const float* w13 = (const float*)d_in[3];
  const float* s13 = (const float*)d_in[4];
  const float* w2  = (const float*)d_in[5];
  const float* s2  = (const float*)d_in[6];
  float* out = (float*)d_out;

  char* ws = (char*)d_ws;
  int* offs = (int*)ws;                                   // 9 ints
  int* ptok = (int*)(ws + 64);                            // 1024 ints
  int* sop  = (int*)(ws + 64 + 4096);                     // 1024 ints
  unsigned short* xg  = (unsigned short*)(ws + 16384);    // [1024][H] bf16 (aliased by buf)
  float*          buf = (float*)(ws + 16384);             // [1024][H] f32
  unsigned short* act = (unsigned short*)(ws + 16384 + (size_t)NPAIR*H_*4);  // [1024][I] bf16

  route_kernel  <<<1, NPAIR, 0, stream>>>(ids, offs, ptok, sop);
  prep_kernel   <<<NPAIR, 256, 0, stream>>>(x, ptok, xg);
  gemm1_kernel  <<<dim3(E_, I_/TN, (NPAIR + TM - 1)/TM), 256, 0, stream>>>(xg, w13, s13, offs, act);
  gemm2_kernel  <<<dim3(E_, H_/TN, (NPAIR + TM - 1)/TM), 256, 0, stream>>>(act, w2, s2, offs, buf);
  combine_kernel<<<(T_*H_/4)/256, 256, 0, stream>>>(buf, sop, tw, out);
}